// Round 3
// baseline (26.775 us; speedup 1.0000x reference)
//
#include <hip/hip_runtime.h>
#include <hip/hip_bf16.h>

// Weighted BCE per-row loss, latency-optimized:
// - Each thread owns VEC=4 float4s (half-rows), read at lane-contiguous
//   addresses tile + k*256 + tid -> every load fully coalesced.
// - 8 outstanding 16B loads per thread (128 B MLP) to cover L2/L3 latency;
//   grid shrinks 15625 -> 3907 blocks.
// - Lane j and j^1 hold the two halves of a row; combine via shfl_xor(1).
// - Weights: wpos = 2*wneg for all columns (wneg = 1,...,1,7), targets are
//   binary -> w = base*(1+t), one log per element:
//     contribution = w * log( t ? p+eps : 1-p+eps )
// - Division replaced by v_rcp_f32 (rel err ~1e-7, harmless vs 0.1 threshold).

#define EPS   1e-8f
#define VEC   4
#define BLOCK 256

__global__ __launch_bounds__(BLOCK) void densenet_loss_kernel(
        const float4* __restrict__ logits,   // 2N float4
        const float4* __restrict__ targets,  // 2N float4
        float* __restrict__ out,             // N floats
        int n4) {                            // n4 = 2N (even)
    const int  tid  = threadIdx.x;
    const int  tile = blockIdx.x * (BLOCK * VEC);
    const bool hi   = (tid & 1);   // odd lane = columns 4..7 (col 7 base weight 7)

    float4 l4[VEC], t4[VEC];
    bool valid[VEC];
#pragma unroll
    for (int k = 0; k < VEC; ++k) {
        int idx = tile + k * BLOCK + tid;
        valid[k] = (idx < n4);
        if (valid[k]) {
            l4[k] = logits[idx];     // compiler hoists all 8 loads together
            t4[k] = targets[idx];
        }
    }

#pragma unroll
    for (int k = 0; k < VEC; ++k) {
        if (!valid[k]) continue;     // n4 even -> row pairs wholly valid/invalid
        const float lv[4] = {l4[k].x, l4[k].y, l4[k].z, l4[k].w};
        const float tv[4] = {t4[k].x, t4[k].y, t4[k].z, t4[k].w};

        float num = 0.f, den = 0.f;
#pragma unroll
        for (int c = 0; c < 4; ++c) {
            float base = (hi && c == 3) ? 7.f : 1.f;
            float ti   = tv[c];
            float w    = base * (1.f + ti);                    // t=0 -> base, t=1 -> 2*base
            float arg  = (ti > 0.5f) ? (lv[c] + EPS) : (1.f - lv[c] + EPS);
            num += w * __logf(arg);
            den += w;
        }

        num += __shfl_xor(num, 1);
        den += __shfl_xor(den, 1);

        if (!hi) {
            int idx = tile + k * BLOCK + tid;
            out[idx >> 1] = -num * __builtin_amdgcn_rcpf(den);
        }
    }
}

extern "C" void kernel_launch(void* const* d_in, const int* in_sizes, int n_in,
                              void* d_out, int out_size, void* d_ws, size_t ws_size,
                              hipStream_t stream) {
    const float4* logits  = (const float4*)d_in[0];
    const float4* targets = (const float4*)d_in[1];
    float* out = (float*)d_out;

    int n4 = in_sizes[0] / 4;                      // number of float4 elements (2 per row)
    int per_block = BLOCK * VEC;                   // 1024 float4s per block
    int grid = (n4 + per_block - 1) / per_block;   // 3907 for N=2M
    densenet_loss_kernel<<<grid, BLOCK, 0, stream>>>(logits, targets, out, n4);
}

// Round 4
// 25.448 us; speedup vs baseline: 1.0521x; 1.0521x over previous
//
#include <hip/hip_runtime.h>
#include <hip/hip_bf16.h>

// Weighted BCE per-row loss — round 4: round-2 structure + packed stores.
// - Each thread owns one float4 (half a row). Lane j / j^1 hold the two
//   halves of row j>>1; combine partial sums via shfl_xor(1).
// - Store packing: even lanes hold the 32 row results of the wave; shfl
//   moves them to lanes 0..31 which issue ONE contiguous 128 B store per
//   wave (previously: every other lane stored 4 B -> half-utilized lines).
// - Weights: wpos = 2*wneg for all columns (wneg = 1,...,1,7), binary
//   targets -> w = base*(1+t), one log per element:
//     contribution = w * log( t ? p+eps : 1-p+eps )
// - rcp instead of exact divide (rel err ~1e-7 vs 0.1 threshold).

#define EPS   1e-8f
#define BLOCK 256

__global__ __launch_bounds__(BLOCK) void densenet_loss_kernel(
        const float4* __restrict__ logits,   // 2N float4
        const float4* __restrict__ targets,  // 2N float4
        float* __restrict__ out,             // N floats
        int n4) {                            // n4 = 2N, multiple of 64 here
    const int j = blockIdx.x * BLOCK + threadIdx.x;
    if (j >= n4) return;

    float4 l4 = logits[j];
    float4 t4 = targets[j];

    const float lv[4] = {l4.x, l4.y, l4.z, l4.w};
    const float tv[4] = {t4.x, t4.y, t4.z, t4.w};

    const bool hi = (j & 1);   // odd float4 = columns 4..7 (col 7 base weight 7)

    float num = 0.f, den = 0.f;
#pragma unroll
    for (int c = 0; c < 4; ++c) {
        float base = (hi && c == 3) ? 7.f : 1.f;
        float ti   = tv[c];
        float w    = base * (1.f + ti);                    // t=0 -> base, t=1 -> 2*base
        float arg  = (ti > 0.5f) ? (lv[c] + EPS) : (1.f - lv[c] + EPS);
        num += w * __logf(arg);
        den += w;
    }

    // combine the two half-rows (lane parity == j parity; block is 256-aligned)
    num += __shfl_xor(num, 1);
    den += __shfl_xor(den, 1);

    float r = -num * __builtin_amdgcn_rcpf(den);   // valid on even lanes

    // pack: lane l<32 takes the result from lane 2l -> contiguous 128 B store
    const int lane = threadIdx.x & 63;
    float rp = __shfl(r, (2 * lane) & 63);
    if (lane < 32) {
        int waveBase = j & ~63;                    // first float4 index of this wave
        out[(waveBase >> 1) + lane] = rp;
    }
}

extern "C" void kernel_launch(void* const* d_in, const int* in_sizes, int n_in,
                              void* d_out, int out_size, void* d_ws, size_t ws_size,
                              hipStream_t stream) {
    const float4* logits  = (const float4*)d_in[0];
    const float4* targets = (const float4*)d_in[1];
    float* out = (float*)d_out;

    int n4 = in_sizes[0] / 4;                 // number of float4 elements (2 per row)
    int grid = (n4 + BLOCK - 1) / BLOCK;      // 15625 exactly for N=2M
    densenet_loss_kernel<<<grid, BLOCK, 0, stream>>>(logits, targets, out, n4);
}